// Round 8
// baseline (177.914 us; speedup 1.0000x reference)
//
#include <hip/hip_runtime.h>

// LightGCN layer: out[d] = in_deg[d]^-1/2 * sum_{e:dst[e]=d} x[src[e]] * out_deg[src[e]]^-1/2
//
// Round 8 (= round 7 with compile fix): feature-split gather. xs (bf16, 9.6 MB)
// doesn't fit the 4 MB per-XCD L2, so the 153.6 MB of random row reads spill to
// Infinity Cache. Split xs into 3 slices of 3.2 MB ([slice][node][16 dwords]);
// gather runs 3 passes, each slice L2-resident. Wave = 1 node, 4 edges in
// parallel (lane = edge_sub*16 + feature_dword), src broadcast via __shfl,
// shfl_xor reduction. Nontemporal loads/stores (scalar form — the builtin
// rejects HIP float2) keep slots/out streams from evicting xs.
// Prep (two-pass multisplit) unchanged from round 6.

#define D_FEAT 96
#define CAP 64
#define PART_SHIFT 8
#define PNODES 256
#define NP_MAX 256
#define EPB 4096
#define OVF_CAP 8192

__device__ __forceinline__ unsigned short f2bf_rne(float f) {
    unsigned u = __float_as_uint(f);
    unsigned r = (u >> 16) & 1u;
    u += 0x7fffu + r;
    return (unsigned short)(u >> 16);
}

// ---------------- pass 1: partition ----------------

__global__ __launch_bounds__(256) void partition_kernel(
        const int* __restrict__ src, const int* __restrict__ dst,
        int n_edges, int np, int stride,
        int* __restrict__ pcur_d, int* __restrict__ pcur_s,
        unsigned* __restrict__ pbuf_d, unsigned short* __restrict__ pbuf_s,
        int* __restrict__ ctr,            // [0]=ovf_n [1]=povf_n [2]=sovf_n
        int* __restrict__ povf_d, int* __restrict__ sovf_d) {
    __shared__ int hcd[NP_MAX], hcs[NP_MAX];
    __shared__ int bd[NP_MAX], bs_[NP_MAX];
    __shared__ int od[NP_MAX], os_[NP_MAX];
    const int base = blockIdx.x * EPB;

    for (int i = threadIdx.x; i < NP_MAX; i += 256) {
        hcd[i] = 0; hcs[i] = 0; od[i] = 0; os_[i] = 0;
    }
    __syncthreads();

    unsigned v[16];
    #pragma unroll
    for (int k = 0; k < 16; ++k) {
        int i = base + (int)threadIdx.x + (k << 8);
        if (i < n_edges) {
            int s = src[i], d = dst[i];
            unsigned pv = (unsigned)d | ((unsigned)s << 16);
            v[k] = pv;
            atomicAdd(&hcd[d >> PART_SHIFT], 1);
            atomicAdd(&hcs[s >> PART_SHIFT], 1);
        }
    }
    __syncthreads();

    for (int p = threadIdx.x; p < np; p += 256) {
        int cd = hcd[p];
        bd[p] = cd ? atomicAdd(&pcur_d[p], cd) : 0;
        int cs = hcs[p];
        bs_[p] = cs ? atomicAdd(&pcur_s[p], cs) : 0;
    }
    __syncthreads();

    #pragma unroll
    for (int k = 0; k < 16; ++k) {
        int i = base + (int)threadIdx.x + (k << 8);
        if (i < n_edges) {
            unsigned pv = v[k];
            int d = (int)(pv & 0xffffu);
            int s = (int)(pv >> 16);
            int pd = d >> PART_SHIFT;
            int j = bd[pd] + atomicAdd(&od[pd], 1);
            if (j < stride) pbuf_d[(size_t)pd * stride + j] = pv;
            else { int k2 = atomicAdd(&ctr[1], 1); if (k2 < OVF_CAP) povf_d[k2] = (int)pv; }
            int ps = s >> PART_SHIFT;
            int j2 = bs_[ps] + atomicAdd(&os_[ps], 1);
            if (j2 < stride) pbuf_s[(size_t)ps * stride + j2] = (unsigned short)s;
            else { int k3 = atomicAdd(&ctr[2], 1); if (k3 < OVF_CAP) sovf_d[k3] = s; }
        }
    }
}

// ---------------- pass 2: bin dst side ----------------

__global__ __launch_bounds__(256) void bin2_kernel(
        const unsigned* __restrict__ pbuf_d, const int* __restrict__ pcur_d,
        int stride, int n_nodes,
        int* __restrict__ cursor, unsigned short* __restrict__ slots,
        int* __restrict__ ctr, int* __restrict__ ovf_d) {
    __shared__ unsigned short lslots[PNODES * CAP];   // 32 KB
    __shared__ int lcnt[PNODES];
    const int b = blockIdx.x;
    const int nbase = b << PART_SHIFT;
    const int nloc = min(PNODES, n_nodes - nbase);

    for (int i = threadIdx.x; i < PNODES; i += 256) lcnt[i] = 0;
    __syncthreads();

    int n = pcur_d[b]; if (n > stride) n = stride;
    for (int i = threadIdx.x; i < n; i += 256) {
        unsigned pv = pbuf_d[(size_t)b * stride + i];
        int dl = (int)(pv & 0xffu);        // d - nbase (partition is 256-aligned)
        int s  = (int)(pv >> 16);
        int pos = atomicAdd(&lcnt[dl], 1);
        if (pos < CAP) lslots[dl * CAP + pos] = (unsigned short)s;
        else { int k = atomicAdd(&ctr[0], 1); if (k < OVF_CAP) ovf_d[k] = (int)pv; }
    }
    __syncthreads();

    for (int i = threadIdx.x; i < nloc; i += 256) cursor[nbase + i] = lcnt[i];
    const unsigned* ls = (const unsigned*)lslots;
    unsigned* gs = (unsigned*)slots + (size_t)nbase * (CAP / 2);
    const int ncopy = nloc * (CAP / 2);
    for (int i = threadIdx.x; i < ncopy; i += 256) gs[i] = ls[i];
}

// ---------------- pass 2: count src side ----------------

__global__ __launch_bounds__(256) void cnt2_kernel(
        const unsigned short* __restrict__ pbuf_s, const int* __restrict__ pcur_s,
        int stride, int n_nodes, int* __restrict__ out_cnt) {
    __shared__ int lcnt[PNODES];
    const int b = blockIdx.x;
    const int nbase = b << PART_SHIFT;
    const int nloc = min(PNODES, n_nodes - nbase);

    for (int i = threadIdx.x; i < PNODES; i += 256) lcnt[i] = 0;
    __syncthreads();

    int n = pcur_s[b]; if (n > stride) n = stride;
    for (int i = threadIdx.x; i < n; i += 256) {
        int s = (int)pbuf_s[(size_t)b * stride + i];
        atomicAdd(&lcnt[s & (PNODES - 1)], 1);
    }
    __syncthreads();

    for (int i = threadIdx.x; i < nloc; i += 256) out_cnt[nbase + i] = lcnt[i];
}

// Exactness fixup for (statistically impossible) partition-buffer overflow.
__global__ void fixup_kernel(int* __restrict__ ctr,
                             const int* __restrict__ povf_d,
                             const int* __restrict__ sovf_d,
                             int* __restrict__ ovf_d,
                             int* __restrict__ cursor,
                             int* __restrict__ out_cnt) {
    int np_ = ctr[1]; if (np_ > OVF_CAP) np_ = OVF_CAP;
    for (int i = threadIdx.x; i < np_; i += 256) {
        unsigned pv = (unsigned)povf_d[i];
        atomicAdd(&cursor[pv & 0xffffu], 1);
        int k = atomicAdd(&ctr[0], 1);
        if (k < OVF_CAP) ovf_d[k] = (int)pv;
    }
    int ns_ = ctr[2]; if (ns_ > OVF_CAP) ns_ = OVF_CAP;
    for (int i = threadIdx.x; i < ns_; i += 256)
        atomicAdd(&out_cnt[(unsigned)sovf_d[i]], 1);
}

// ---------------- convert: sliced bf16 xs ----------------
// xs layout: slice p (p=0..2) at xs + p*n_nodes*16; row = 16 dwords =
// features [32p, 32p+32). xs[(p*n_nodes + node)*16 + fj] packs features
// 32p+2fj, 32p+2fj+1 (pre-scaled by out_deg^-1/2).

__global__ void convert_kernel(const float* __restrict__ x,
                               const int* __restrict__ out_cnt,
                               unsigned* __restrict__ xs, int n_nodes) {
    int t = blockIdx.x * blockDim.x + threadIdx.x;
    int n_total = n_nodes * 48;
    if (t >= n_total) return;
    int node = t / 48;
    int j = t - node * 48;
    int c = out_cnt[node];
    float w = rsqrtf((float)(c < 1 ? 1 : c));
    float2 v = *(const float2*)(x + (size_t)node * D_FEAT + j * 2);
    unsigned lo = f2bf_rne(v.x * w);
    unsigned hi = f2bf_rne(v.y * w);
    int p = j >> 4, fj = j & 15;
    xs[((size_t)p * n_nodes + node) * 16 + fj] = lo | (hi << 16);
}

// ---------------- gather: one pass over one feature slice ----------------
// Wave = 1 node. lane = sub*16 + fj: 4 edges in parallel (sub), 16 feature
// dwords (fj). Src ids broadcast from prefetched slot regs via __shfl.

__global__ __launch_bounds__(256) void gather3_kernel(
        const unsigned* __restrict__ xsp,          // slice base [n_nodes][16]
        const unsigned short* __restrict__ slots,
        const int* __restrict__ cursor,
        float* __restrict__ outp,                  // out + 32*p
        int n_nodes) {
    int wid  = threadIdx.x >> 6;
    int lane = threadIdx.x & 63;
    int node = __builtin_amdgcn_readfirstlane(blockIdx.x * 4 + wid);
    if (node >= n_nodes) return;

    int cnt_all = __builtin_amdgcn_readfirstlane(cursor[node]);
    int cnt = cnt_all < CAP ? cnt_all : CAP;

    const int sub = lane >> 4;     // which of 4 parallel edges
    const int fj  = lane & 15;     // feature dword within slice

    float accx = 0.f, accy = 0.f;
    if (cnt > 0) {
        int idx  = lane < cnt ? lane : cnt - 1;
        int sval = (int)__builtin_nontemporal_load(&slots[node * CAP + idx]);

        for (int e = 0; e < cnt; e += 4) {
            int ee = e + sub;
            bool valid = ee < cnt;
            int s = __shfl(sval, valid ? ee : cnt - 1, 64);
            unsigned u = xsp[(size_t)s * 16 + fj];
            if (valid) {
                accx += __uint_as_float(u << 16);
                accy += __uint_as_float(u & 0xffff0000u);
            }
        }
        // reduce the 4 edge-subgroups: lanes {l, l^16, l^32, l^48}
        accx += __shfl_xor(accx, 32, 64); accy += __shfl_xor(accy, 32, 64);
        accx += __shfl_xor(accx, 16, 64); accy += __shfl_xor(accy, 16, 64);
    }

    float sc = rsqrtf((float)(cnt_all < 1 ? 1 : cnt_all));
    if (sub == 0) {   // lanes 0..15 hold the totals; contiguous 128 B store
        float* op = outp + (size_t)node * D_FEAT + fj * 2;
        __builtin_nontemporal_store(accx * sc, op);
        __builtin_nontemporal_store(accy * sc, op + 1);
    }
}

// Fix up edges with dst in-degree > CAP (packed v entries). Adds on gather output.
__global__ void overflow_kernel(const float* __restrict__ x,
                                const int* __restrict__ out_cnt,
                                const int* __restrict__ cursor,
                                const int* __restrict__ ctr,
                                const int* __restrict__ ovf_d,
                                float* __restrict__ out) {
    int count = ctr[0];
    if (count > OVF_CAP) count = OVF_CAP;
    int total = count * 24;
    int stride_t = gridDim.x * blockDim.x;
    for (int i = blockIdx.x * blockDim.x + threadIdx.x; i < total; i += stride_t) {
        int k = i / 24, c = i % 24;
        unsigned pv = (unsigned)ovf_d[k];
        int d = (int)(pv & 0xffffu);
        int s = (int)(pv >> 16);
        int co = out_cnt[s], ci = cursor[d];
        float w = rsqrtf((float)(co < 1 ? 1 : co)) * rsqrtf((float)(ci < 1 ? 1 : ci));
        const float4 v = *(const float4*)(x + (size_t)s * D_FEAT + c * 4);
        float* o = out + (size_t)d * D_FEAT + c * 4;
        unsafeAtomicAdd(o + 0, v.x * w);
        unsafeAtomicAdd(o + 1, v.y * w);
        unsafeAtomicAdd(o + 2, v.z * w);
        unsafeAtomicAdd(o + 3, v.w * w);
    }
}

// ---------------- fallback (round-1 atomic scatter, any size) ----------------

__global__ void degree_kernel(const int* __restrict__ src,
                              const int* __restrict__ dst,
                              int* __restrict__ out_cnt,
                              int* __restrict__ in_cnt, int n_edges) {
    int i = blockIdx.x * blockDim.x + threadIdx.x;
    if (i < n_edges) {
        atomicAdd(&out_cnt[src[i]], 1);
        atomicAdd(&in_cnt[dst[i]], 1);
    }
}

__global__ void scale_kernel(float* __restrict__ osc, float* __restrict__ isc, int n) {
    int i = blockIdx.x * blockDim.x + threadIdx.x;
    if (i < n) {
        int c0 = ((const int*)osc)[i];
        int c1 = ((const int*)isc)[i];
        osc[i] = rsqrtf((float)(c0 < 1 ? 1 : c0));
        isc[i] = rsqrtf((float)(c1 < 1 ? 1 : c1));
    }
}

__global__ void scatter_kernel(const float* __restrict__ x,
                               const int* __restrict__ src,
                               const int* __restrict__ dst,
                               const float* __restrict__ osc,
                               const float* __restrict__ isc,
                               float* __restrict__ out, int n_edges) {
    int idx = blockIdx.x * blockDim.x + threadIdx.x;
    int e = idx / 24, c = idx % 24;
    if (e >= n_edges) return;
    int s = src[e], d = dst[e];
    float w = osc[s] * isc[d];
    const float4 v = *(const float4*)(x + (size_t)s * D_FEAT + c * 4);
    float* o = out + (size_t)d * D_FEAT + c * 4;
    unsafeAtomicAdd(o + 0, v.x * w);
    unsafeAtomicAdd(o + 1, v.y * w);
    unsafeAtomicAdd(o + 2, v.z * w);
    unsafeAtomicAdd(o + 3, v.w * w);
}

// ---------------- launcher ----------------

extern "C" void kernel_launch(void* const* d_in, const int* in_sizes, int n_in,
                              void* d_out, int out_size, void* d_ws, size_t ws_size,
                              hipStream_t stream) {
    const float* x  = (const float*)d_in[0];
    const int* src  = (const int*)d_in[1];
    const int* dst  = (const int*)d_in[2];
    float* out      = (float*)d_out;

    const int n_edges = in_sizes[1];
    const int n_nodes = in_sizes[0] / D_FEAT;

    const int np = (n_nodes + PNODES - 1) / PNODES;
    const int avg = n_edges / (np > 0 ? np : 1);
    const int stride = avg + avg / 4 + 1024;

    const size_t pbuf_words  = (size_t)np * stride;          // dst buffer (uint)
    const size_t pbufs_words = (pbuf_words + 1) / 2;         // src buffer (ushort)

    // ws layout (int32 units):
    int* pcur_d  = (int*)d_ws;            // 256
    int* pcur_s  = pcur_d + 256;          // 256
    int* ctr     = pcur_d + 512;          // 3 (pad to 1024)
    int* ovf_d   = pcur_d + 1024;         // OVF_CAP (packed v)
    int* povf_d  = ovf_d + OVF_CAP;       // OVF_CAP
    int* sovf_d  = povf_d + OVF_CAP;      // OVF_CAP
    int* out_cnt = sovf_d + OVF_CAP;      // 65536
    int* cursor  = out_cnt + 65536;       // 65536
    unsigned* pbuf_dst = (unsigned*)(cursor + 65536);
    unsigned short* pbuf_src = (unsigned short*)(pbuf_dst + pbuf_words);
    unsigned* xs = pbuf_dst + pbuf_words + pbufs_words;      // 3 slices x n_nodes*16
    unsigned short* slots = (unsigned short*)(xs + (size_t)n_nodes * 48);

    const size_t needed = ((size_t)1024 + 3 * OVF_CAP + 2 * 65536 + pbuf_words +
                           pbufs_words + (size_t)n_nodes * 48 +
                           (size_t)n_nodes * (CAP / 2)) * 4;

    if (ws_size >= needed && n_nodes <= 65536 && np <= NP_MAX) {
        (void)hipMemsetAsync(d_ws, 0, 1024 * sizeof(int), stream);

        partition_kernel<<<(n_edges + EPB - 1) / EPB, 256, 0, stream>>>(
            src, dst, n_edges, np, stride, pcur_d, pcur_s,
            pbuf_dst, pbuf_src, ctr, povf_d, sovf_d);

        bin2_kernel<<<np, 256, 0, stream>>>(
            pbuf_dst, pcur_d, stride, n_nodes, cursor, slots, ctr, ovf_d);

        cnt2_kernel<<<np, 256, 0, stream>>>(
            pbuf_src, pcur_s, stride, n_nodes, out_cnt);

        fixup_kernel<<<1, 256, 0, stream>>>(
            ctr, povf_d, sovf_d, ovf_d, cursor, out_cnt);

        const int n_pairs = n_nodes * 48;
        convert_kernel<<<(n_pairs + 255) / 256, 256, 0, stream>>>(
            x, out_cnt, xs, n_nodes);

        const int gblk = (n_nodes + 3) / 4;
        for (int p = 0; p < 3; ++p) {
            gather3_kernel<<<gblk, 256, 0, stream>>>(
                xs + (size_t)p * n_nodes * 16, slots, cursor,
                out + 32 * p, n_nodes);
        }

        overflow_kernel<<<32, 256, 0, stream>>>(
            x, out_cnt, cursor, ctr, ovf_d, out);
    } else {
        // fallback: atomic scatter (round-1 path, any size)
        float* osc = (float*)d_ws;
        float* isc = osc + 65536;
        (void)hipMemsetAsync(d_ws, 0, 2 * 65536 * sizeof(int), stream);
        (void)hipMemsetAsync(d_out, 0, (size_t)out_size * sizeof(float), stream);
        degree_kernel<<<(n_edges + 255) / 256, 256, 0, stream>>>(
            src, dst, (int*)osc, (int*)isc, n_edges);
        scale_kernel<<<(n_nodes + 255) / 256, 256, 0, stream>>>(osc, isc, n_nodes);
        const int total = n_edges * 24;
        scatter_kernel<<<(total + 255) / 256, 256, 0, stream>>>(
            x, src, dst, osc, isc, out, n_edges);
    }
}

// Round 9
// 141.660 us; speedup vs baseline: 1.2559x; 1.2559x over previous
//
#include <hip/hip_runtime.h>

// LightGCN layer: out[d] = in_deg[d]^-1/2 * sum_{e:dst[e]=d} x[src[e]] * out_deg[src[e]]^-1/2
//
// Round 9: revert round-8's feature-split (regressed: per-pass fixed costs x3).
// Round-6 structure + two changes:
//  - gather: 16-deep unroll -> 16 outstanding loads/wave (was 8). The gather is
//    latency x concurrency bound (~3.4 TB/s observed vs 34.5 TB/s L2 ceiling).
//  - bin2+cnt2 fused into one kernel (same partition, one launch less).

#define D_FEAT 96
#define CAP 64
#define PART_SHIFT 8
#define PNODES 256
#define NP_MAX 256
#define EPB 4096
#define OVF_CAP 8192

__device__ __forceinline__ unsigned short f2bf_rne(float f) {
    unsigned u = __float_as_uint(f);
    unsigned r = (u >> 16) & 1u;
    u += 0x7fffu + r;
    return (unsigned short)(u >> 16);
}

// ---------------- pass 1: partition ----------------

__global__ __launch_bounds__(256) void partition_kernel(
        const int* __restrict__ src, const int* __restrict__ dst,
        int n_edges, int np, int stride,
        int* __restrict__ pcur_d, int* __restrict__ pcur_s,
        unsigned* __restrict__ pbuf_d, unsigned short* __restrict__ pbuf_s,
        int* __restrict__ ctr,            // [0]=ovf_n [1]=povf_n [2]=sovf_n
        int* __restrict__ povf_d, int* __restrict__ sovf_d) {
    __shared__ int hcd[NP_MAX], hcs[NP_MAX];
    __shared__ int bd[NP_MAX], bs_[NP_MAX];
    __shared__ int od[NP_MAX], os_[NP_MAX];
    const int base = blockIdx.x * EPB;

    for (int i = threadIdx.x; i < NP_MAX; i += 256) {
        hcd[i] = 0; hcs[i] = 0; od[i] = 0; os_[i] = 0;
    }
    __syncthreads();

    unsigned v[16];
    #pragma unroll
    for (int k = 0; k < 16; ++k) {
        int i = base + (int)threadIdx.x + (k << 8);
        if (i < n_edges) {
            int s = src[i], d = dst[i];
            unsigned pv = (unsigned)d | ((unsigned)s << 16);
            v[k] = pv;
            atomicAdd(&hcd[d >> PART_SHIFT], 1);
            atomicAdd(&hcs[s >> PART_SHIFT], 1);
        }
    }
    __syncthreads();

    for (int p = threadIdx.x; p < np; p += 256) {
        int cd = hcd[p];
        bd[p] = cd ? atomicAdd(&pcur_d[p], cd) : 0;
        int cs = hcs[p];
        bs_[p] = cs ? atomicAdd(&pcur_s[p], cs) : 0;
    }
    __syncthreads();

    #pragma unroll
    for (int k = 0; k < 16; ++k) {
        int i = base + (int)threadIdx.x + (k << 8);
        if (i < n_edges) {
            unsigned pv = v[k];
            int d = (int)(pv & 0xffffu);
            int s = (int)(pv >> 16);
            int pd = d >> PART_SHIFT;
            int j = bd[pd] + atomicAdd(&od[pd], 1);
            if (j < stride) pbuf_d[(size_t)pd * stride + j] = pv;
            else { int k2 = atomicAdd(&ctr[1], 1); if (k2 < OVF_CAP) povf_d[k2] = (int)pv; }
            int ps = s >> PART_SHIFT;
            int j2 = bs_[ps] + atomicAdd(&os_[ps], 1);
            if (j2 < stride) pbuf_s[(size_t)ps * stride + j2] = (unsigned short)s;
            else { int k3 = atomicAdd(&ctr[2], 1); if (k3 < OVF_CAP) sovf_d[k3] = s; }
        }
    }
}

// ---------------- pass 2: bin dst side + count src side (fused) ----------------

__global__ __launch_bounds__(256) void bincnt_kernel(
        const unsigned* __restrict__ pbuf_d, const int* __restrict__ pcur_d,
        const unsigned short* __restrict__ pbuf_s, const int* __restrict__ pcur_s,
        int stride, int n_nodes,
        int* __restrict__ cursor, int* __restrict__ out_cnt,
        unsigned short* __restrict__ slots,
        int* __restrict__ ctr, int* __restrict__ ovf_d) {
    __shared__ unsigned short lslots[PNODES * CAP];   // 32 KB
    __shared__ int lcnt[PNODES];
    __shared__ int lout[PNODES];
    const int b = blockIdx.x;
    const int nbase = b << PART_SHIFT;
    const int nloc = min(PNODES, n_nodes - nbase);

    for (int i = threadIdx.x; i < PNODES; i += 256) { lcnt[i] = 0; lout[i] = 0; }
    __syncthreads();

    // dst side: bin into slots
    int n = pcur_d[b]; if (n > stride) n = stride;
    for (int i = threadIdx.x; i < n; i += 256) {
        unsigned pv = pbuf_d[(size_t)b * stride + i];
        int dl = (int)(pv & 0xffu);        // d - nbase (partition is 256-aligned)
        int s  = (int)(pv >> 16);
        int pos = atomicAdd(&lcnt[dl], 1);
        if (pos < CAP) lslots[dl * CAP + pos] = (unsigned short)s;
        else { int k = atomicAdd(&ctr[0], 1); if (k < OVF_CAP) ovf_d[k] = (int)pv; }
    }
    // src side: histogram out-degree
    int n2 = pcur_s[b]; if (n2 > stride) n2 = stride;
    for (int i = threadIdx.x; i < n2; i += 256) {
        int s = (int)pbuf_s[(size_t)b * stride + i];
        atomicAdd(&lout[s & (PNODES - 1)], 1);
    }
    __syncthreads();

    for (int i = threadIdx.x; i < nloc; i += 256) {
        cursor[nbase + i]  = lcnt[i];
        out_cnt[nbase + i] = lout[i];
    }
    const unsigned* ls = (const unsigned*)lslots;
    unsigned* gs = (unsigned*)slots + (size_t)nbase * (CAP / 2);
    const int ncopy = nloc * (CAP / 2);
    for (int i = threadIdx.x; i < ncopy; i += 256) gs[i] = ls[i];
}

// Exactness fixup for (statistically impossible) partition-buffer overflow.
__global__ void fixup_kernel(int* __restrict__ ctr,
                             const int* __restrict__ povf_d,
                             const int* __restrict__ sovf_d,
                             int* __restrict__ ovf_d,
                             int* __restrict__ cursor,
                             int* __restrict__ out_cnt) {
    int np_ = ctr[1]; if (np_ > OVF_CAP) np_ = OVF_CAP;
    for (int i = threadIdx.x; i < np_; i += 256) {
        unsigned pv = (unsigned)povf_d[i];
        atomicAdd(&cursor[pv & 0xffffu], 1);
        int k = atomicAdd(&ctr[0], 1);
        if (k < OVF_CAP) ovf_d[k] = (int)pv;
    }
    int ns_ = ctr[2]; if (ns_ > OVF_CAP) ns_ = OVF_CAP;
    for (int i = threadIdx.x; i < ns_; i += 256)
        atomicAdd(&out_cnt[(unsigned)sovf_d[i]], 1);
}

// ---------------- convert: bf16 pre-scaled xs ----------------
// xs[node*48 + j] packs features 2j, 2j+1 (scaled by out_deg^-1/2).

__global__ void convert_kernel(const float* __restrict__ x,
                               const int* __restrict__ out_cnt,
                               unsigned* __restrict__ xs, int n_total) {
    int t = blockIdx.x * blockDim.x + threadIdx.x;
    if (t >= n_total) return;
    int node = t / 48;
    int j = t - node * 48;
    int c = out_cnt[node];
    float w = rsqrtf((float)(c < 1 ? 1 : c));
    float2 v = *(const float2*)(x + (size_t)node * D_FEAT + j * 2);
    unsigned lo = f2bf_rne(v.x * w);
    unsigned hi = f2bf_rne(v.y * w);
    xs[t] = lo | (hi << 16);
}

// ---------------- gather: wave per node, 16-deep unrolled ----------------

__global__ __launch_bounds__(256) void gather_kernel(
        const unsigned* __restrict__ xs,
        const unsigned short* __restrict__ slots,
        const int* __restrict__ cursor,
        float* __restrict__ out, int n_nodes) {
    int wid  = threadIdx.x >> 6;
    int lane = threadIdx.x & 63;
    int node = __builtin_amdgcn_readfirstlane(blockIdx.x * 4 + wid);
    if (node >= n_nodes) return;

    int cnt_all = __builtin_amdgcn_readfirstlane(cursor[node]);
    int cnt = cnt_all < CAP ? cnt_all : CAP;

    float accx = 0.f, accy = 0.f;
    const bool act = lane < 48;        // 48 lanes x (2 bf16) = 96 features

    if (cnt > 0) {
        int idx  = lane < cnt ? lane : cnt - 1;
        int sval = (int)slots[node * CAP + idx];   // lane l holds slot l's src id

        int e = 0;
        for (; e + 16 <= cnt; e += 16) {
            if (act) {
                unsigned u[16];
                #pragma unroll
                for (int k = 0; k < 16; ++k) {
                    int s = __builtin_amdgcn_readlane(sval, e + k);
                    u[k] = xs[s * 48 + lane];
                }
                #pragma unroll
                for (int k = 0; k < 16; ++k) {
                    accx += __uint_as_float(u[k] << 16);
                    accy += __uint_as_float(u[k] & 0xffff0000u);
                }
            }
        }
        for (; e + 4 <= cnt; e += 4) {
            if (act) {
                unsigned u[4];
                #pragma unroll
                for (int k = 0; k < 4; ++k) {
                    int s = __builtin_amdgcn_readlane(sval, e + k);
                    u[k] = xs[s * 48 + lane];
                }
                #pragma unroll
                for (int k = 0; k < 4; ++k) {
                    accx += __uint_as_float(u[k] << 16);
                    accy += __uint_as_float(u[k] & 0xffff0000u);
                }
            }
        }
        for (; e < cnt; ++e) {
            if (act) {
                int s = __builtin_amdgcn_readlane(sval, e);
                unsigned u0 = xs[s * 48 + lane];
                accx += __uint_as_float(u0 << 16);
                accy += __uint_as_float(u0 & 0xffff0000u);
            }
        }
    }

    float sc = rsqrtf((float)(cnt_all < 1 ? 1 : cnt_all));
    if (act) {
        float* op = out + (size_t)node * D_FEAT + lane * 2;
        op[0] = accx * sc;
        op[1] = accy * sc;
    }
}

// Fix up edges with dst in-degree > CAP (packed v entries). Adds on gather output.
__global__ void overflow_kernel(const float* __restrict__ x,
                                const int* __restrict__ out_cnt,
                                const int* __restrict__ cursor,
                                const int* __restrict__ ctr,
                                const int* __restrict__ ovf_d,
                                float* __restrict__ out) {
    int count = ctr[0];
    if (count > OVF_CAP) count = OVF_CAP;
    int total = count * 24;
    int stride_t = gridDim.x * blockDim.x;
    for (int i = blockIdx.x * blockDim.x + threadIdx.x; i < total; i += stride_t) {
        int k = i / 24, c = i % 24;
        unsigned pv = (unsigned)ovf_d[k];
        int d = (int)(pv & 0xffffu);
        int s = (int)(pv >> 16);
        int co = out_cnt[s], ci = cursor[d];
        float w = rsqrtf((float)(co < 1 ? 1 : co)) * rsqrtf((float)(ci < 1 ? 1 : ci));
        const float4 v = *(const float4*)(x + (size_t)s * D_FEAT + c * 4);
        float* o = out + (size_t)d * D_FEAT + c * 4;
        unsafeAtomicAdd(o + 0, v.x * w);
        unsafeAtomicAdd(o + 1, v.y * w);
        unsafeAtomicAdd(o + 2, v.z * w);
        unsafeAtomicAdd(o + 3, v.w * w);
    }
}

// ---------------- fallback (round-1 atomic scatter, any size) ----------------

__global__ void degree_kernel(const int* __restrict__ src,
                              const int* __restrict__ dst,
                              int* __restrict__ out_cnt,
                              int* __restrict__ in_cnt, int n_edges) {
    int i = blockIdx.x * blockDim.x + threadIdx.x;
    if (i < n_edges) {
        atomicAdd(&out_cnt[src[i]], 1);
        atomicAdd(&in_cnt[dst[i]], 1);
    }
}

__global__ void scale_kernel(float* __restrict__ osc, float* __restrict__ isc, int n) {
    int i = blockIdx.x * blockDim.x + threadIdx.x;
    if (i < n) {
        int c0 = ((const int*)osc)[i];
        int c1 = ((const int*)isc)[i];
        osc[i] = rsqrtf((float)(c0 < 1 ? 1 : c0));
        isc[i] = rsqrtf((float)(c1 < 1 ? 1 : c1));
    }
}

__global__ void scatter_kernel(const float* __restrict__ x,
                               const int* __restrict__ src,
                               const int* __restrict__ dst,
                               const float* __restrict__ osc,
                               const float* __restrict__ isc,
                               float* __restrict__ out, int n_edges) {
    int idx = blockIdx.x * blockDim.x + threadIdx.x;
    int e = idx / 24, c = idx % 24;
    if (e >= n_edges) return;
    int s = src[e], d = dst[e];
    float w = osc[s] * isc[d];
    const float4 v = *(const float4*)(x + (size_t)s * D_FEAT + c * 4);
    float* o = out + (size_t)d * D_FEAT + c * 4;
    unsafeAtomicAdd(o + 0, v.x * w);
    unsafeAtomicAdd(o + 1, v.y * w);
    unsafeAtomicAdd(o + 2, v.z * w);
    unsafeAtomicAdd(o + 3, v.w * w);
}

// ---------------- launcher ----------------

extern "C" void kernel_launch(void* const* d_in, const int* in_sizes, int n_in,
                              void* d_out, int out_size, void* d_ws, size_t ws_size,
                              hipStream_t stream) {
    const float* x  = (const float*)d_in[0];
    const int* src  = (const int*)d_in[1];
    const int* dst  = (const int*)d_in[2];
    float* out      = (float*)d_out;

    const int n_edges = in_sizes[1];
    const int n_nodes = in_sizes[0] / D_FEAT;

    const int np = (n_nodes + PNODES - 1) / PNODES;
    const int avg = n_edges / (np > 0 ? np : 1);
    const int stride = avg + avg / 4 + 1024;

    const size_t pbuf_words  = (size_t)np * stride;          // dst buffer (uint)
    const size_t pbufs_words = (pbuf_words + 1) / 2;         // src buffer (ushort)

    // ws layout (int32 units):
    int* pcur_d  = (int*)d_ws;            // 256
    int* pcur_s  = pcur_d + 256;          // 256
    int* ctr     = pcur_d + 512;          // 3 (pad to 1024)
    int* ovf_d   = pcur_d + 1024;         // OVF_CAP (packed v)
    int* povf_d  = ovf_d + OVF_CAP;       // OVF_CAP
    int* sovf_d  = povf_d + OVF_CAP;      // OVF_CAP
    int* out_cnt = sovf_d + OVF_CAP;      // 65536
    int* cursor  = out_cnt + 65536;       // 65536
    unsigned* pbuf_dst = (unsigned*)(cursor + 65536);
    unsigned short* pbuf_src = (unsigned short*)(pbuf_dst + pbuf_words);
    unsigned* xs = pbuf_dst + pbuf_words + pbufs_words;
    unsigned short* slots = (unsigned short*)(xs + (size_t)n_nodes * 48);

    const size_t needed = ((size_t)1024 + 3 * OVF_CAP + 2 * 65536 + pbuf_words +
                           pbufs_words + (size_t)n_nodes * 48 +
                           (size_t)n_nodes * (CAP / 2)) * 4;

    if (ws_size >= needed && n_nodes <= 65536 && np <= NP_MAX) {
        (void)hipMemsetAsync(d_ws, 0, 1024 * sizeof(int), stream);

        partition_kernel<<<(n_edges + EPB - 1) / EPB, 256, 0, stream>>>(
            src, dst, n_edges, np, stride, pcur_d, pcur_s,
            pbuf_dst, pbuf_src, ctr, povf_d, sovf_d);

        bincnt_kernel<<<np, 256, 0, stream>>>(
            pbuf_dst, pcur_d, pbuf_src, pcur_s, stride, n_nodes,
            cursor, out_cnt, slots, ctr, ovf_d);

        fixup_kernel<<<1, 256, 0, stream>>>(
            ctr, povf_d, sovf_d, ovf_d, cursor, out_cnt);

        const int n_pairs = n_nodes * 48;
        convert_kernel<<<(n_pairs + 255) / 256, 256, 0, stream>>>(
            x, out_cnt, xs, n_pairs);

        gather_kernel<<<(n_nodes + 3) / 4, 256, 0, stream>>>(
            xs, slots, cursor, out, n_nodes);

        overflow_kernel<<<32, 256, 0, stream>>>(
            x, out_cnt, cursor, ctr, ovf_d, out);
    } else {
        // fallback: atomic scatter (round-1 path, any size)
        float* osc = (float*)d_ws;
        float* isc = osc + 65536;
        (void)hipMemsetAsync(d_ws, 0, 2 * 65536 * sizeof(int), stream);
        (void)hipMemsetAsync(d_out, 0, (size_t)out_size * sizeof(float), stream);
        degree_kernel<<<(n_edges + 255) / 256, 256, 0, stream>>>(
            src, dst, (int*)osc, (int*)isc, n_edges);
        scale_kernel<<<(n_nodes + 255) / 256, 256, 0, stream>>>(osc, isc, n_nodes);
        const int total = n_edges * 24;
        scatter_kernel<<<(total + 255) / 256, 256, 0, stream>>>(
            x, src, dst, osc, isc, out, n_edges);
    }
}